// Round 10
// baseline (228.116 us; speedup 1.0000x reference)
//
#include <hip/hip_runtime.h>
#include <hip/hip_fp16.h>
#include <math.h>

// Problem constants (fixed by setup_inputs)
#define BATCH   2
#define LQ      21760
#define CDIM    256
#define NHEADS  8
#define NLEV    4
#define NPTS    4
#define HDIM    32
#define QT      16           // queries per block; 43520/16 = 2720 blocks
#define PROJ_LDH 392         // f16 proj stride (384 cols + 8 pad)

// NOTE (rounds 5-7): f16-packed feat + __hfma2 (v_pk_fma_f16) produced
// deterministic wrong results (absmax 0.634, bit-identical across 3 different
// consumer structures). bf16 feat + scalar f32 fmaf is hardware-verified.
// NOTE (round 8): __launch_bounds__ min-waves >= 6 caused scratch traffic
// (WRITE_SIZE 81->376 MB). Keep min-waves <= 5.
// NOTE (round 9): hoisting tuples/accumulators as ARRAYS (l_off[16], a[16])
// caused ~300 MB scratch traffic (rule: runtime-indexed/aggregate arrays ->
// localMem). This round: same algorithm, all named scalars.

typedef short  bf16x8 __attribute__((ext_vector_type(8)));
typedef float  f32x4  __attribute__((ext_vector_type(4)));
typedef unsigned int u32x4 __attribute__((ext_vector_type(4)));
typedef unsigned short u16x8 __attribute__((ext_vector_type(8)));

static __device__ __host__ inline unsigned short f2bf(float x) {
    unsigned int u = __builtin_bit_cast(unsigned int, x);
    unsigned int r = (u + 0x7fff + ((u >> 16) & 1)) >> 16;   // RNE
    return (unsigned short)r;
}
static __device__ inline unsigned int pack2h(float a, float b) {
    __half2 h = __floats2half2_rn(a, b);
    return __builtin_bit_cast(unsigned int, h);
}
static __device__ inline float2 unpack2h(unsigned int u) {
    return __half22float2(__builtin_bit_cast(__half2, u));
}
static __device__ inline float bfhi(unsigned int u) {   // high bf16 -> f32
    return __builtin_bit_cast(float, u & 0xffff0000u);
}
static __device__ inline float bflo(unsigned int u) {   // low bf16 -> f32
    return __builtin_bit_cast(float, u << 16);
}

// ---- pack feat f32 -> bf16 into ws ----
__global__ __launch_bounds__(256) void pack_feat(
    const float* __restrict__ f, unsigned short* __restrict__ o)
{
    const size_t i8 = ((size_t)blockIdx.x * 256 + threadIdx.x) * 8;
    const float4 v0 = *(const float4*)(f + i8);
    const float4 v1 = *(const float4*)(f + i8 + 4);
    u16x8 pk;
    pk[0] = f2bf(v0.x); pk[1] = f2bf(v0.y); pk[2] = f2bf(v0.z); pk[3] = f2bf(v0.w);
    pk[4] = f2bf(v1.x); pk[5] = f2bf(v1.y); pk[6] = f2bf(v1.z); pk[7] = f2bf(v1.w);
    *(u16x8*)(o + i8) = pk;
}

// ---- pack W into bf16 B-fragment-major layout ----
__global__ __launch_bounds__(256) void pack_w(
    const float* __restrict__ Woff, const float* __restrict__ Wattn,
    const float* __restrict__ Wout, unsigned short* __restrict__ wsB,
    unsigned short* __restrict__ wsO)
{
    const int id = blockIdx.x * 256 + threadIdx.x;   // 0 .. 20479
    bf16x8 pk;
    if (id < 12288) {
        const int lane = id & 63, s = (id >> 6) & 7, tn = id >> 9;
        const int col = tn * 16 + (lane & 15);
        const int k0  = s * 32 + (lane >> 4) * 8;
        #pragma unroll
        for (int i = 0; i < 8; ++i) {
            const int k = k0 + i;
            const float w = (col < 256) ? Woff[(size_t)k * 256 + col]
                                        : Wattn[(size_t)k * 128 + (col - 256)];
            pk[i] = (short)f2bf(w);
        }
        *(bf16x8*)(wsB + (size_t)id * 8) = pk;
    } else {
        const int id2 = id - 12288;
        const int lane = id2 & 63, s = (id2 >> 6) & 7, tn = id2 >> 9;
        const int col = tn * 16 + (lane & 15);
        const int k0  = s * 32 + (lane >> 4) * 8;
        #pragma unroll
        for (int i = 0; i < 8; ++i)
            pk[i] = (short)f2bf(Wout[(size_t)(k0 + i) * 256 + col]);
        *(bf16x8*)(wsO + (size_t)id2 * 8) = pk;
    }
}

// A-frag reader: xqb is [16 rows][512 B] bf16, column-XOR-swizzled:
// element (row,k) lives at byte row*512 + ((k*2) ^ ((row&7)<<4))
static __device__ inline void load_afrags(const unsigned char* xqb, int lane, bf16x8* af) {
    const int row = lane & 15;
    const int kg8 = (lane >> 4) * 8;
    const int sw  = (row & 7) << 4;
    const int base = row * 512;
    #pragma unroll
    for (int s = 0; s < 8; ++s) {
        const int byte = base + (((s * 32 + kg8) * 2) ^ sw);
        af[s] = *(const bf16x8*)(xqb + byte);
    }
}

template<bool BF16F>
__global__ __launch_bounds__(256, 4) void msda_fused(
    const float* __restrict__ query,     // [B][LQ][256]
    const float* __restrict__ refp,      // [B][LQ][2]
    const float* __restrict__ feat,      // [B][LQ][256] f32
    const unsigned short* __restrict__ featbf,   // [B][LQ][256] bf16 (if BF16F)
    const float* __restrict__ boff,      // [256]
    const float* __restrict__ battn,     // [128]
    const float* __restrict__ bout,      // [256]
    const unsigned short* __restrict__ wsB,   // packed [Woff|Wattn] frags
    const unsigned short* __restrict__ wsO,   // packed Wout frags
    float* __restrict__ out)             // [B][LQ][256]
{
    __shared__ __align__(16) unsigned char xqb[QT * 512];   // bf16 A-tile (query, then mid)
    __shared__ __align__(16) __half projh[QT * PROJ_LDH];   // f16 [off(256)|attn(128)] per q

    const int t    = threadIdx.x;
    const int lane = t & 63;
    const int wid  = t >> 6;
    const int q0   = blockIdx.x * QT;
    const int b    = q0 / LQ;

    // ---- Phase A: stage 16 query rows as swizzled bf16 ----
    {
        const float4* src = (const float4*)(query + (size_t)q0 * CDIM);
        #pragma unroll
        for (int i = 0; i < 4; ++i) {
            const int idx = t + i * 256;          // 0..1023 float4s
            const int row = idx >> 6;             // 64 float4 per row
            const int k4  = (idx & 63) * 4;       // element k base
            const float4 v = src[idx];
            uint2 w;
            w.x = (unsigned int)f2bf(v.x) | ((unsigned int)f2bf(v.y) << 16);
            w.y = (unsigned int)f2bf(v.z) | ((unsigned int)f2bf(v.w) << 16);
            const int byte = row * 512 + ((k4 * 2) ^ ((row & 7) << 4));
            *(uint2*)(xqb + byte) = w;
        }
    }
    __syncthreads();

    // ---- Phase B: projh[q][c] = query . [Woff|Wattn] + bias via MFMA ----
    {
        bf16x8 af[8];
        load_afrags(xqb, lane, af);
        const int colb = lane & 15;
        const int r0   = (lane >> 4) * 4;
        #pragma unroll
        for (int j = 0; j < 6; ++j) {
            const int tn  = wid * 6 + j;          // 0..23
            const int col = tn * 16 + colb;
            const float bv = (col < 256) ? boff[col] : battn[col - 256];
            f32x4 acc = {bv, bv, bv, bv};
            const bf16x8* bp = (const bf16x8*)wsB + (size_t)tn * 8 * 64 + lane;
            #pragma unroll
            for (int s = 0; s < 8; ++s)
                acc = __builtin_amdgcn_mfma_f32_16x16x32_bf16(af[s], bp[(size_t)s * 64], acc, 0, 0, 0);
            #pragma unroll
            for (int r = 0; r < 4; ++r)
                projh[(r0 + r) * PROJ_LDH + col] = __float2half(acc[r]);
        }
    }
    __syncthreads();

    // ---- Phase C: softmax over the 16 attn logits per (q, h) ----
    if (t < QT * NHEADS) {
        const int q = t >> 3, h = t & 7;
        __half* a = projh + q * PROJ_LDH + 256 + h * 16;
        float v[16];
        #pragma unroll
        for (int j = 0; j < 16; ++j) v[j] = __half2float(a[j]);
        float m = v[0];
        #pragma unroll
        for (int j = 1; j < 16; ++j) m = fmaxf(m, v[j]);
        float s = 0.f;
        #pragma unroll
        for (int j = 0; j < 16; ++j) { v[j] = __expf(v[j] - m); s += v[j]; }
        const float inv = 1.f / s;
        #pragma unroll
        for (int j = 0; j < 16; ++j) a[j] = __float2half(v[j] * inv);
    }
    __syncthreads();

    // ---- Phase D0: each thread builds 8 tuples for its (q_own, h_own, half) ----
    // tuple (q,h,lp) lives in lane (q&3)*16 + h*2 + (lp>>3), register k = lp&7
    // (producer mapping + xor-exchange + 16ch consumer: HW-proven by round 9 pass)
    int r_off[8]; int r_w01[8]; int r_w23[8];
    {
        const int q_own = t >> 4;
        const int h_own = (t >> 1) & 7;
        const int lpb   = (t & 1) * 8;
        const float rx = refp[(size_t)(q0 + q_own) * 2 + 0];
        const float ry = refp[(size_t)(q0 + q_own) * 2 + 1];
        const int LW[4] = {128, 64, 32, 16};
        const int LS[4] = {0, 16384, 20480, 21504};
        #pragma unroll
        for (int k = 0; k < 8; ++k) {
            const int lp = lpb + k;
            const int l = lp >> 2, p = lp & 3;
            const int Wl = LW[l], Hl = LW[l];
            const unsigned int oxy = *(const unsigned int*)(projh + q_own * PROJ_LDH
                                        + ((h_own * NLEV + l) * NPTS + p) * 2);
            const float2 oo = unpack2h(oxy);
            const float aw = __half2float(projh[q_own * PROJ_LDH + 256 + h_own * 16 + lp]);
            const float x = rx * (float)Wl + oo.x - 0.5f;
            const float y = ry * (float)Hl + oo.y - 0.5f;
            const float x0f = floorf(x), y0f = floorf(y);
            const float fx = x - x0f, fy = y - y0f;
            const int ix = (int)x0f, iy = (int)y0f;
            const bool vx0 = (ix >= 0) & (ix < Wl), vx1 = (ix >= -1) & (ix < Wl - 1);
            const bool vy0 = (iy >= 0) & (iy < Hl), vy1 = (iy >= -1) & (iy < Hl - 1);
            const float w00 = (vx0 & vy0) ? (1.f - fx) * (1.f - fy) * aw : 0.f;
            const float w01 = (vx1 & vy0) ? fx * (1.f - fy) * aw : 0.f;
            const float w10 = (vx0 & vy1) ? (1.f - fx) * fy * aw : 0.f;
            const float w11 = (vx1 & vy1) ? fx * fy * aw : 0.f;
            r_off[k] = LS[l] + iy * Wl + ix;
            r_w01[k] = (int)pack2h(w00, w01);
            r_w23[k] = (int)pack2h(w10, w11);
        }
    }
    // no barrier needed: producer = this lane or lane^1 (same wave)

    // ---- exchange to NAMED SCALARS (no arrays -> no scratch) ----
    const bool hiHalf = (t & 1) != 0;     // this thread produced lp 8..15
    int offL0, offL1, offL2, offL3, offL4, offL5, offL6, offL7;
    int offH0, offH1, offH2, offH3, offH4, offH5, offH6, offH7;
    unsigned w01L0, w01L1, w01L2, w01L3, w01L4, w01L5, w01L6, w01L7;
    unsigned w01H0, w01H1, w01H2, w01H3, w01H4, w01H5, w01H6, w01H7;
    unsigned w23L0, w23L1, w23L2, w23L3, w23L4, w23L5, w23L6, w23L7;
    unsigned w23H0, w23H1, w23H2, w23H3, w23H4, w23H5, w23H6, w23H7;
    #define XCHG(K)                                                           \
    {   const int no = __shfl_xor(r_off[K], 1);                               \
        const int n1 = __shfl_xor(r_w01[K], 1);                               \
        const int n2 = __shfl_xor(r_w23[K], 1);                               \
        offL##K = hiHalf ? no : r_off[K];                                     \
        w01L##K = (unsigned)(hiHalf ? n1 : r_w01[K]);                         \
        w23L##K = (unsigned)(hiHalf ? n2 : r_w23[K]);                         \
        offH##K = hiHalf ? r_off[K] : no;                                     \
        w01H##K = (unsigned)(hiHalf ? r_w01[K] : n1);                         \
        w23H##K = (unsigned)(hiHalf ? r_w23[K] : n2); }
    XCHG(0) XCHG(1) XCHG(2) XCHG(3) XCHG(4) XCHG(5) XCHG(6) XCHG(7)
    #undef XCHG

    // ---- Phase D1: gather; thread t -> (q = t>>4, h = (t>>1)&7, d16 = t&1) ----
    // 16 channels/thread, all 16 tuples in scalar registers, 128 independent loads.
    {
        const int q   = t >> 4;
        const int h   = (t >> 1) & 7;
        const int d16 = t & 1;
        const int chb = h * HDIM + d16 * 16;      // 16-channel window base
        float c0 = 0.f, c1 = 0.f, c2 = 0.f, c3 = 0.f;
        float c4 = 0.f, c5 = 0.f, c6 = 0.f, c7 = 0.f;
        float c8 = 0.f, c9 = 0.f, c10 = 0.f, c11 = 0.f;
        float c12 = 0.f, c13 = 0.f, c14 = 0.f, c15 = 0.f;

        if (BF16F) {
            const unsigned short* fb = featbf + (size_t)b * LQ * CDIM + chb;
            #define ACC8A(W, V)                                               \
                c0 = fmaf(W, bflo(V[0]), c0);  c1 = fmaf(W, bfhi(V[0]), c1);  \
                c2 = fmaf(W, bflo(V[1]), c2);  c3 = fmaf(W, bfhi(V[1]), c3);  \
                c4 = fmaf(W, bflo(V[2]), c4);  c5 = fmaf(W, bfhi(V[2]), c5);  \
                c6 = fmaf(W, bflo(V[3]), c6);  c7 = fmaf(W, bfhi(V[3]), c7);
            #define ACC8B(W, V)                                               \
                c8  = fmaf(W, bflo(V[0]), c8);  c9  = fmaf(W, bfhi(V[0]), c9);  \
                c10 = fmaf(W, bflo(V[1]), c10); c11 = fmaf(W, bfhi(V[1]), c11); \
                c12 = fmaf(W, bflo(V[2]), c12); c13 = fmaf(W, bfhi(V[2]), c13); \
                c14 = fmaf(W, bflo(V[3]), c14); c15 = fmaf(W, bfhi(V[3]), c15);
            #define GB(OFF, W01, W23, WL)                                     \
            {   const float2 wlo = unpack2h(W01);                             \
                const float2 whi = unpack2h(W23);                             \
                const int o0 = (wlo.x != 0.f) ? (OFF)            : 0;         \
                const int o1 = (wlo.y != 0.f) ? (OFF) + 1        : 0;         \
                const int o2 = (whi.x != 0.f) ? (OFF) + (WL)     : 0;         \
                const int o3 = (whi.y != 0.f) ? (OFF) + (WL) + 1 : 0;         \
                const u32x4 vA0 = *(const u32x4*)(fb + (long)o0 * CDIM);      \
                const u32x4 vB0 = *(const u32x4*)(fb + (long)o0 * CDIM + 8);  \
                const u32x4 vA1 = *(const u32x4*)(fb + (long)o1 * CDIM);      \
                const u32x4 vB1 = *(const u32x4*)(fb + (long)o1 * CDIM + 8);  \
                const u32x4 vA2 = *(const u32x4*)(fb + (long)o2 * CDIM);      \
                const u32x4 vB2 = *(const u32x4*)(fb + (long)o2 * CDIM + 8);  \
                const u32x4 vA3 = *(const u32x4*)(fb + (long)o3 * CDIM);      \
                const u32x4 vB3 = *(const u32x4*)(fb + (long)o3 * CDIM + 8);  \
                ACC8A(wlo.x, vA0) ACC8B(wlo.x, vB0)                           \
                ACC8A(wlo.y, vA1) ACC8B(wlo.y, vB1)                           \
                ACC8A(whi.x, vA2) ACC8B(whi.x, vB2)                           \
                ACC8A(whi.y, vA3) ACC8B(whi.y, vB3) }
            GB(offL0, w01L0, w23L0, 128)   // lp 0..3  -> level 0, W=128
            GB(offL1, w01L1, w23L1, 128)
            GB(offL2, w01L2, w23L2, 128)
            GB(offL3, w01L3, w23L3, 128)
            GB(offL4, w01L4, w23L4, 64)    // lp 4..7  -> level 1, W=64
            GB(offL5, w01L5, w23L5, 64)
            GB(offL6, w01L6, w23L6, 64)
            GB(offL7, w01L7, w23L7, 64)
            GB(offH0, w01H0, w23H0, 32)    // lp 8..11 -> level 2, W=32
            GB(offH1, w01H1, w23H1, 32)
            GB(offH2, w01H2, w23H2, 32)
            GB(offH3, w01H3, w23H3, 32)
            GB(offH4, w01H4, w23H4, 16)    // lp 12..15 -> level 3, W=16
            GB(offH5, w01H5, w23H5, 16)
            GB(offH6, w01H6, w23H6, 16)
            GB(offH7, w01H7, w23H7, 16)
            #undef GB
            #undef ACC8A
            #undef ACC8B
        } else {
            const float* fbf = feat + (size_t)b * LQ * CDIM + chb;
            #define ACCF(W, O)                                                \
            {   const f32x4 u0 = *(const f32x4*)(fbf + (long)(O) * CDIM);     \
                const f32x4 u1 = *(const f32x4*)(fbf + (long)(O) * CDIM + 4); \
                const f32x4 u2 = *(const f32x4*)(fbf + (long)(O) * CDIM + 8); \
                const f32x4 u3 = *(const f32x4*)(fbf + (long)(O) * CDIM + 12);\
                c0  = fmaf(W, u0[0], c0);  c1  = fmaf(W, u0[1], c1);          \
                c2  = fmaf(W, u0[2], c2);  c3  = fmaf(W, u0[3], c3);          \
                c4  = fmaf(W, u1[0], c4);  c5  = fmaf(W, u1[1], c5);          \
                c6  = fmaf(W, u1[2], c6);  c7  = fmaf(W, u1[3], c7);          \
                c8  = fmaf(W, u2[0], c8);  c9  = fmaf(W, u2[1], c9);          \
                c10 = fmaf(W, u2[2], c10); c11 = fmaf(W, u2[3], c11);         \
                c12 = fmaf(W, u3[0], c12); c13 = fmaf(W, u3[1], c13);         \
                c14 = fmaf(W, u3[2], c14); c15 = fmaf(W, u3[3], c15); }
            #define GF(OFF, W01, W23, WL)                                     \
            {   const float2 wlo = unpack2h(W01);                             \
                const float2 whi = unpack2h(W23);                             \
                const int o0 = (wlo.x != 0.f) ? (OFF)            : 0;         \
                const int o1 = (wlo.y != 0.f) ? (OFF) + 1        : 0;         \
                const int o2 = (whi.x != 0.f) ? (OFF) + (WL)     : 0;         \
                const int o3 = (whi.y != 0.f) ? (OFF) + (WL) + 1 : 0;         \
                ACCF(wlo.x, o0) ACCF(wlo.y, o1) ACCF(whi.x, o2) ACCF(whi.y, o3) }
            GF(offL0, w01L0, w23L0, 128)
            GF(offL1, w01L1, w23L1, 128)
            GF(offL2, w01L2, w23L2, 128)
            GF(offL3, w01L3, w23L3, 128)
            GF(offL4, w01L4, w23L4, 64)
            GF(offL5, w01L5, w23L5, 64)
            GF(offL6, w01L6, w23L6, 64)
            GF(offL7, w01L7, w23L7, 64)
            GF(offH0, w01H0, w23H0, 32)
            GF(offH1, w01H1, w23H1, 32)
            GF(offH2, w01H2, w23H2, 32)
            GF(offH3, w01H3, w23H3, 32)
            GF(offH4, w01H4, w23H4, 16)
            GF(offH5, w01H5, w23H5, 16)
            GF(offH6, w01H6, w23H6, 16)
            GF(offH7, w01H7, w23H7, 16)
            #undef GF
            #undef ACCF
        }

        // write mid[q][chb .. chb+15] as swizzled bf16 (2 x 16B stores; r9-proven)
        const unsigned wv0 = (unsigned)f2bf(c0)  | ((unsigned)f2bf(c1)  << 16);
        const unsigned wv1 = (unsigned)f2bf(c2)  | ((unsigned)f2bf(c3)  << 16);
        const unsigned wv2 = (unsigned)f2bf(c4)  | ((unsigned)f2bf(c5)  << 16);
        const unsigned wv3 = (unsigned)f2bf(c6)  | ((unsigned)f2bf(c7)  << 16);
        const unsigned wv4 = (unsigned)f2bf(c8)  | ((unsigned)f2bf(c9)  << 16);
        const unsigned wv5 = (unsigned)f2bf(c10) | ((unsigned)f2bf(c11) << 16);
        const unsigned wv6 = (unsigned)f2bf(c12) | ((unsigned)f2bf(c13) << 16);
        const unsigned wv7 = (unsigned)f2bf(c14) | ((unsigned)f2bf(c15) << 16);
        const int sw = (q & 7) << 4;
        const u32x4 s0 = {wv0, wv1, wv2, wv3};
        const u32x4 s1 = {wv4, wv5, wv6, wv7};
        *(u32x4*)(xqb + q * 512 + ((chb * 2) ^ sw))      = s0;
        *(u32x4*)(xqb + q * 512 + ((chb * 2 + 16) ^ sw)) = s1;
    }
    __syncthreads();

    // ---- Phase E: out[q][n] = mid . Wout + bout via MFMA, direct global store ----
    {
        bf16x8 af[8];
        load_afrags(xqb, lane, af);
        const int colb = lane & 15;
        const int r0   = (lane >> 4) * 4;
        #pragma unroll
        for (int j = 0; j < 4; ++j) {
            const int tn  = wid * 4 + j;          // 0..15
            const int col = tn * 16 + colb;
            const float bv = bout[col];
            f32x4 acc = {bv, bv, bv, bv};
            const bf16x8* bp = (const bf16x8*)wsO + (size_t)tn * 8 * 64 + lane;
            #pragma unroll
            for (int s = 0; s < 8; ++s)
                acc = __builtin_amdgcn_mfma_f32_16x16x32_bf16(af[s], bp[(size_t)s * 64], acc, 0, 0, 0);
            #pragma unroll
            for (int r = 0; r < 4; ++r)
                out[(size_t)(q0 + r0 + r) * CDIM + col] = acc[r];
        }
    }
}

extern "C" void kernel_launch(void* const* d_in, const int* in_sizes, int n_in,
                              void* d_out, int out_size, void* d_ws, size_t ws_size,
                              hipStream_t stream) {
    const float* query = (const float*)d_in[0];
    const float* refp  = (const float*)d_in[1];
    const float* feat  = (const float*)d_in[2];
    const float* Woff  = (const float*)d_in[5];
    const float* boff  = (const float*)d_in[6];
    const float* Wattn = (const float*)d_in[7];
    const float* battn = (const float*)d_in[8];
    const float* Wout  = (const float*)d_in[9];
    const float* bout  = (const float*)d_in[10];
    float* out = (float*)d_out;

    unsigned short* ws = (unsigned short*)d_ws;
    const size_t feat_us = (size_t)BATCH * LQ * CDIM;        // 11,141,120 ushorts
    const size_t need    = (feat_us + 98304 + 65536) * 2;    // bytes
    const bool usebf = ws_size >= need;

    const int nrows = BATCH * LQ;            // 43520

    if (usebf) {
        unsigned short* featbf = ws;
        unsigned short* wsB = ws + feat_us;
        unsigned short* wsO = wsB + 98304;
        pack_feat<<<dim3((unsigned)(feat_us / 8 / 256)), dim3(256), 0, stream>>>(feat, featbf);
        pack_w<<<dim3(80), dim3(256), 0, stream>>>(Woff, Wattn, Wout, wsB, wsO);
        msda_fused<true><<<dim3(nrows / QT), dim3(256), 0, stream>>>(
            query, refp, feat, featbf, boff, battn, bout, wsB, wsO, out);
    } else {
        unsigned short* wsB = ws;
        unsigned short* wsO = ws + 98304;
        pack_w<<<dim3(80), dim3(256), 0, stream>>>(Woff, Wattn, Wout, wsB, wsO);
        msda_fused<false><<<dim3(nrows / QT), dim3(256), 0, stream>>>(
            query, refp, feat, (const unsigned short*)nullptr, boff, battn, bout, wsB, wsO, out);
    }
}

// Round 11
// 158.967 us; speedup vs baseline: 1.4350x; 1.4350x over previous
//
#include <hip/hip_runtime.h>
#include <hip/hip_fp16.h>
#include <math.h>

// Problem constants (fixed by setup_inputs)
#define BATCH   2
#define LQ      21760
#define CDIM    256
#define NHEADS  8
#define NLEV    4
#define NPTS    4
#define HDIM    32
#define QT      16           // queries per block; 43520/16 = 2720 blocks
#define PROJ_LDH 392         // f16 proj stride (384 cols + 8 pad)

// NOTE (rounds 5-7): f16-packed feat + __hfma2 (v_pk_fma_f16) produced
// deterministic wrong results (absmax 0.634, bit-identical across 3 different
// consumer structures). bf16 feat + scalar f32 fmaf is hardware-verified.
// NOTE (round 8): __launch_bounds__ min-waves 7 -> cap 73 VGPR -> spill
// (WRITE_SIZE 81->376 MB).
// NOTE (rounds 9-10): hoisted-tuple D1 at cap 128 ((256,4)) ALSO spills
// (~300 MB scratch; arrays vs named scalars identical -> live-range pressure
// from deep load batching, not rule-#20). This round: cap 170 via (256,3).

typedef short  bf16x8 __attribute__((ext_vector_type(8)));
typedef float  f32x4  __attribute__((ext_vector_type(4)));
typedef unsigned int u32x4 __attribute__((ext_vector_type(4)));
typedef unsigned short u16x8 __attribute__((ext_vector_type(8)));

static __device__ __host__ inline unsigned short f2bf(float x) {
    unsigned int u = __builtin_bit_cast(unsigned int, x);
    unsigned int r = (u + 0x7fff + ((u >> 16) & 1)) >> 16;   // RNE
    return (unsigned short)r;
}
static __device__ inline unsigned int pack2h(float a, float b) {
    __half2 h = __floats2half2_rn(a, b);
    return __builtin_bit_cast(unsigned int, h);
}
static __device__ inline float2 unpack2h(unsigned int u) {
    return __half22float2(__builtin_bit_cast(__half2, u));
}
static __device__ inline float bfhi(unsigned int u) {   // high bf16 -> f32
    return __builtin_bit_cast(float, u & 0xffff0000u);
}
static __device__ inline float bflo(unsigned int u) {   // low bf16 -> f32
    return __builtin_bit_cast(float, u << 16);
}

// ---- pack feat f32 -> bf16 into ws ----
__global__ __launch_bounds__(256) void pack_feat(
    const float* __restrict__ f, unsigned short* __restrict__ o)
{
    const size_t i8 = ((size_t)blockIdx.x * 256 + threadIdx.x) * 8;
    const float4 v0 = *(const float4*)(f + i8);
    const float4 v1 = *(const float4*)(f + i8 + 4);
    u16x8 pk;
    pk[0] = f2bf(v0.x); pk[1] = f2bf(v0.y); pk[2] = f2bf(v0.z); pk[3] = f2bf(v0.w);
    pk[4] = f2bf(v1.x); pk[5] = f2bf(v1.y); pk[6] = f2bf(v1.z); pk[7] = f2bf(v1.w);
    *(u16x8*)(o + i8) = pk;
}

// ---- pack W into bf16 B-fragment-major layout ----
__global__ __launch_bounds__(256) void pack_w(
    const float* __restrict__ Woff, const float* __restrict__ Wattn,
    const float* __restrict__ Wout, unsigned short* __restrict__ wsB,
    unsigned short* __restrict__ wsO)
{
    const int id = blockIdx.x * 256 + threadIdx.x;   // 0 .. 20479
    bf16x8 pk;
    if (id < 12288) {
        const int lane = id & 63, s = (id >> 6) & 7, tn = id >> 9;
        const int col = tn * 16 + (lane & 15);
        const int k0  = s * 32 + (lane >> 4) * 8;
        #pragma unroll
        for (int i = 0; i < 8; ++i) {
            const int k = k0 + i;
            const float w = (col < 256) ? Woff[(size_t)k * 256 + col]
                                        : Wattn[(size_t)k * 128 + (col - 256)];
            pk[i] = (short)f2bf(w);
        }
        *(bf16x8*)(wsB + (size_t)id * 8) = pk;
    } else {
        const int id2 = id - 12288;
        const int lane = id2 & 63, s = (id2 >> 6) & 7, tn = id2 >> 9;
        const int col = tn * 16 + (lane & 15);
        const int k0  = s * 32 + (lane >> 4) * 8;
        #pragma unroll
        for (int i = 0; i < 8; ++i)
            pk[i] = (short)f2bf(Wout[(size_t)(k0 + i) * 256 + col]);
        *(bf16x8*)(wsO + (size_t)id2 * 8) = pk;
    }
}

// A-frag reader: xqb is [16 rows][512 B] bf16, column-XOR-swizzled:
// element (row,k) lives at byte row*512 + ((k*2) ^ ((row&7)<<4))
static __device__ inline void load_afrags(const unsigned char* xqb, int lane, bf16x8* af) {
    const int row = lane & 15;
    const int kg8 = (lane >> 4) * 8;
    const int sw  = (row & 7) << 4;
    const int base = row * 512;
    #pragma unroll
    for (int s = 0; s < 8; ++s) {
        const int byte = base + (((s * 32 + kg8) * 2) ^ sw);
        af[s] = *(const bf16x8*)(xqb + byte);
    }
}

template<bool BF16F>
__global__ __launch_bounds__(256, 3) void msda_fused(
    const float* __restrict__ query,     // [B][LQ][256]
    const float* __restrict__ refp,      // [B][LQ][2]
    const float* __restrict__ feat,      // [B][LQ][256] f32
    const unsigned short* __restrict__ featbf,   // [B][LQ][256] bf16 (if BF16F)
    const float* __restrict__ boff,      // [256]
    const float* __restrict__ battn,     // [128]
    const float* __restrict__ bout,      // [256]
    const unsigned short* __restrict__ wsB,   // packed [Woff|Wattn] frags
    const unsigned short* __restrict__ wsO,   // packed Wout frags
    float* __restrict__ out)             // [B][LQ][256]
{
    __shared__ __align__(16) unsigned char xqb[QT * 512];   // bf16 A-tile (query, then mid)
    __shared__ __align__(16) __half projh[QT * PROJ_LDH];   // f16 [off(256)|attn(128)] per q

    const int t    = threadIdx.x;
    const int lane = t & 63;
    const int wid  = t >> 6;
    const int q0   = blockIdx.x * QT;
    const int b    = q0 / LQ;

    // ---- Phase A: stage 16 query rows as swizzled bf16 ----
    {
        const float4* src = (const float4*)(query + (size_t)q0 * CDIM);
        #pragma unroll
        for (int i = 0; i < 4; ++i) {
            const int idx = t + i * 256;          // 0..1023 float4s
            const int row = idx >> 6;             // 64 float4 per row
            const int k4  = (idx & 63) * 4;       // element k base
            const float4 v = src[idx];
            uint2 w;
            w.x = (unsigned int)f2bf(v.x) | ((unsigned int)f2bf(v.y) << 16);
            w.y = (unsigned int)f2bf(v.z) | ((unsigned int)f2bf(v.w) << 16);
            const int byte = row * 512 + ((k4 * 2) ^ ((row & 7) << 4));
            *(uint2*)(xqb + byte) = w;
        }
    }
    __syncthreads();

    // ---- Phase B: projh[q][c] = query . [Woff|Wattn] + bias via MFMA ----
    {
        bf16x8 af[8];
        load_afrags(xqb, lane, af);
        const int colb = lane & 15;
        const int r0   = (lane >> 4) * 4;
        #pragma unroll
        for (int j = 0; j < 6; ++j) {
            const int tn  = wid * 6 + j;          // 0..23
            const int col = tn * 16 + colb;
            const float bv = (col < 256) ? boff[col] : battn[col - 256];
            f32x4 acc = {bv, bv, bv, bv};
            const bf16x8* bp = (const bf16x8*)wsB + (size_t)tn * 8 * 64 + lane;
            #pragma unroll
            for (int s = 0; s < 8; ++s)
                acc = __builtin_amdgcn_mfma_f32_16x16x32_bf16(af[s], bp[(size_t)s * 64], acc, 0, 0, 0);
            #pragma unroll
            for (int r = 0; r < 4; ++r)
                projh[(r0 + r) * PROJ_LDH + col] = __float2half(acc[r]);
        }
    }
    __syncthreads();

    // ---- Phase C: softmax over the 16 attn logits per (q, h) ----
    if (t < QT * NHEADS) {
        const int q = t >> 3, h = t & 7;
        __half* a = projh + q * PROJ_LDH + 256 + h * 16;
        float v[16];
        #pragma unroll
        for (int j = 0; j < 16; ++j) v[j] = __half2float(a[j]);
        float m = v[0];
        #pragma unroll
        for (int j = 1; j < 16; ++j) m = fmaxf(m, v[j]);
        float s = 0.f;
        #pragma unroll
        for (int j = 0; j < 16; ++j) { v[j] = __expf(v[j] - m); s += v[j]; }
        const float inv = 1.f / s;
        #pragma unroll
        for (int j = 0; j < 16; ++j) a[j] = __float2half(v[j] * inv);
    }
    __syncthreads();

    // ---- Phase D0: each thread builds 8 tuples for its (q_own, h_own, half) ----
    // tuple (q,h,lp) lives in lane (q&3)*16 + h*2 + (lp>>3), register k = lp&7
    // (producer mapping + xor-exchange + 16ch consumer: HW-proven by rounds 9/10)
    int r_off[8]; int r_w01[8]; int r_w23[8];
    {
        const int q_own = t >> 4;
        const int h_own = (t >> 1) & 7;
        const int lpb   = (t & 1) * 8;
        const float rx = refp[(size_t)(q0 + q_own) * 2 + 0];
        const float ry = refp[(size_t)(q0 + q_own) * 2 + 1];
        const int LW[4] = {128, 64, 32, 16};
        const int LS[4] = {0, 16384, 20480, 21504};
        #pragma unroll
        for (int k = 0; k < 8; ++k) {
            const int lp = lpb + k;
            const int l = lp >> 2, p = lp & 3;
            const int Wl = LW[l], Hl = LW[l];
            const unsigned int oxy = *(const unsigned int*)(projh + q_own * PROJ_LDH
                                        + ((h_own * NLEV + l) * NPTS + p) * 2);
            const float2 oo = unpack2h(oxy);
            const float aw = __half2float(projh[q_own * PROJ_LDH + 256 + h_own * 16 + lp]);
            const float x = rx * (float)Wl + oo.x - 0.5f;
            const float y = ry * (float)Hl + oo.y - 0.5f;
            const float x0f = floorf(x), y0f = floorf(y);
            const float fx = x - x0f, fy = y - y0f;
            const int ix = (int)x0f, iy = (int)y0f;
            const bool vx0 = (ix >= 0) & (ix < Wl), vx1 = (ix >= -1) & (ix < Wl - 1);
            const bool vy0 = (iy >= 0) & (iy < Hl), vy1 = (iy >= -1) & (iy < Hl - 1);
            const float w00 = (vx0 & vy0) ? (1.f - fx) * (1.f - fy) * aw : 0.f;
            const float w01 = (vx1 & vy0) ? fx * (1.f - fy) * aw : 0.f;
            const float w10 = (vx0 & vy1) ? (1.f - fx) * fy * aw : 0.f;
            const float w11 = (vx1 & vy1) ? fx * fy * aw : 0.f;
            r_off[k] = LS[l] + iy * Wl + ix;
            r_w01[k] = (int)pack2h(w00, w01);
            r_w23[k] = (int)pack2h(w10, w11);
        }
    }
    // no barrier needed: producer = this lane or lane^1 (same wave)

    // ---- exchange to named scalars ----
    const bool hiHalf = (t & 1) != 0;     // this thread produced lp 8..15
    int offL0, offL1, offL2, offL3, offL4, offL5, offL6, offL7;
    int offH0, offH1, offH2, offH3, offH4, offH5, offH6, offH7;
    unsigned w01L0, w01L1, w01L2, w01L3, w01L4, w01L5, w01L6, w01L7;
    unsigned w01H0, w01H1, w01H2, w01H3, w01H4, w01H5, w01H6, w01H7;
    unsigned w23L0, w23L1, w23L2, w23L3, w23L4, w23L5, w23L6, w23L7;
    unsigned w23H0, w23H1, w23H2, w23H3, w23H4, w23H5, w23H6, w23H7;
    #define XCHG(K)                                                           \
    {   const int no = __shfl_xor(r_off[K], 1);                               \
        const int n1 = __shfl_xor(r_w01[K], 1);                               \
        const int n2 = __shfl_xor(r_w23[K], 1);                               \
        offL##K = hiHalf ? no : r_off[K];                                     \
        w01L##K = (unsigned)(hiHalf ? n1 : r_w01[K]);                         \
        w23L##K = (unsigned)(hiHalf ? n2 : r_w23[K]);                         \
        offH##K = hiHalf ? r_off[K] : no;                                     \
        w01H##K = (unsigned)(hiHalf ? r_w01[K] : n1);                         \
        w23H##K = (unsigned)(hiHalf ? r_w23[K] : n2); }
    XCHG(0) XCHG(1) XCHG(2) XCHG(3) XCHG(4) XCHG(5) XCHG(6) XCHG(7)
    #undef XCHG

    // ---- Phase D1: gather; thread t -> (q = t>>4, h = (t>>1)&7, d16 = t&1) ----
    // 16 channels/thread, all 16 tuples in scalar registers, 128 independent loads.
    {
        const int q   = t >> 4;
        const int h   = (t >> 1) & 7;
        const int d16 = t & 1;
        const int chb = h * HDIM + d16 * 16;      // 16-channel window base
        float c0 = 0.f, c1 = 0.f, c2 = 0.f, c3 = 0.f;
        float c4 = 0.f, c5 = 0.f, c6 = 0.f, c7 = 0.f;
        float c8 = 0.f, c9 = 0.f, c10 = 0.f, c11 = 0.f;
        float c12 = 0.f, c13 = 0.f, c14 = 0.f, c15 = 0.f;

        if (BF16F) {
            const unsigned short* fb = featbf + (size_t)b * LQ * CDIM + chb;
            #define ACC8A(W, V)                                               \
                c0 = fmaf(W, bflo(V[0]), c0);  c1 = fmaf(W, bfhi(V[0]), c1);  \
                c2 = fmaf(W, bflo(V[1]), c2);  c3 = fmaf(W, bfhi(V[1]), c3);  \
                c4 = fmaf(W, bflo(V[2]), c4);  c5 = fmaf(W, bfhi(V[2]), c5);  \
                c6 = fmaf(W, bflo(V[3]), c6);  c7 = fmaf(W, bfhi(V[3]), c7);
            #define ACC8B(W, V)                                               \
                c8  = fmaf(W, bflo(V[0]), c8);  c9  = fmaf(W, bfhi(V[0]), c9);  \
                c10 = fmaf(W, bflo(V[1]), c10); c11 = fmaf(W, bfhi(V[1]), c11); \
                c12 = fmaf(W, bflo(V[2]), c12); c13 = fmaf(W, bfhi(V[2]), c13); \
                c14 = fmaf(W, bflo(V[3]), c14); c15 = fmaf(W, bfhi(V[3]), c15);
            #define GB(OFF, W01, W23, WL)                                     \
            {   const float2 wlo = unpack2h(W01);                             \
                const float2 whi = unpack2h(W23);                             \
                const int o0 = (wlo.x != 0.f) ? (OFF)            : 0;         \
                const int o1 = (wlo.y != 0.f) ? (OFF) + 1        : 0;         \
                const int o2 = (whi.x != 0.f) ? (OFF) + (WL)     : 0;         \
                const int o3 = (whi.y != 0.f) ? (OFF) + (WL) + 1 : 0;         \
                const u32x4 vA0 = *(const u32x4*)(fb + (long)o0 * CDIM);      \
                const u32x4 vB0 = *(const u32x4*)(fb + (long)o0 * CDIM + 8);  \
                const u32x4 vA1 = *(const u32x4*)(fb + (long)o1 * CDIM);      \
                const u32x4 vB1 = *(const u32x4*)(fb + (long)o1 * CDIM + 8);  \
                const u32x4 vA2 = *(const u32x4*)(fb + (long)o2 * CDIM);      \
                const u32x4 vB2 = *(const u32x4*)(fb + (long)o2 * CDIM + 8);  \
                const u32x4 vA3 = *(const u32x4*)(fb + (long)o3 * CDIM);      \
                const u32x4 vB3 = *(const u32x4*)(fb + (long)o3 * CDIM + 8);  \
                ACC8A(wlo.x, vA0) ACC8B(wlo.x, vB0)                           \
                ACC8A(wlo.y, vA1) ACC8B(wlo.y, vB1)                           \
                ACC8A(whi.x, vA2) ACC8B(whi.x, vB2)                           \
                ACC8A(whi.y, vA3) ACC8B(whi.y, vB3) }
            GB(offL0, w01L0, w23L0, 128)   // lp 0..3  -> level 0, W=128
            GB(offL1, w01L1, w23L1, 128)
            GB(offL2, w01L2, w23L2, 128)
            GB(offL3, w01L3, w23L3, 128)
            GB(offL4, w01L4, w23L4, 64)    // lp 4..7  -> level 1, W=64
            GB(offL5, w01L5, w23L5, 64)
            GB(offL6, w01L6, w23L6, 64)
            GB(offL7, w01L7, w23L7, 64)
            GB(offH0, w01H0, w23H0, 32)    // lp 8..11 -> level 2, W=32
            GB(offH1, w01H1, w23H1, 32)
            GB(offH2, w01H2, w23H2, 32)
            GB(offH3, w01H3, w23H3, 32)
            GB(offH4, w01H4, w23H4, 16)    // lp 12..15 -> level 3, W=16
            GB(offH5, w01H5, w23H5, 16)
            GB(offH6, w01H6, w23H6, 16)
            GB(offH7, w01H7, w23H7, 16)
            #undef GB
            #undef ACC8A
            #undef ACC8B
        } else {
            const float* fbf = feat + (size_t)b * LQ * CDIM + chb;
            #define ACCF(W, O)                                                \
            {   const f32x4 u0 = *(const f32x4*)(fbf + (long)(O) * CDIM);     \
                const f32x4 u1 = *(const f32x4*)(fbf + (long)(O) * CDIM + 4); \
                const f32x4 u2 = *(const f32x4*)(fbf + (long)(O) * CDIM + 8); \
                const f32x4 u3 = *(const f32x4*)(fbf + (long)(O) * CDIM + 12);\
                c0  = fmaf(W, u0[0], c0);  c1  = fmaf(W, u0[1], c1);          \
                c2  = fmaf(W, u0[2], c2);  c3  = fmaf(W, u0[3], c3);          \
                c4  = fmaf(W, u1[0], c4);  c5  = fmaf(W, u1[1], c5);          \
                c6  = fmaf(W, u1[2], c6);  c7  = fmaf(W, u1[3], c7);          \
                c8  = fmaf(W, u2[0], c8);  c9  = fmaf(W, u2[1], c9);          \
                c10 = fmaf(W, u2[2], c10); c11 = fmaf(W, u2[3], c11);         \
                c12 = fmaf(W, u3[0], c12); c13 = fmaf(W, u3[1], c13);         \
                c14 = fmaf(W, u3[2], c14); c15 = fmaf(W, u3[3], c15); }
            #define GF(OFF, W01, W23, WL)                                     \
            {   const float2 wlo = unpack2h(W01);                             \
                const float2 whi = unpack2h(W23);                             \
                const int o0 = (wlo.x != 0.f) ? (OFF)            : 0;         \
                const int o1 = (wlo.y != 0.f) ? (OFF) + 1        : 0;         \
                const int o2 = (whi.x != 0.f) ? (OFF) + (WL)     : 0;         \
                const int o3 = (whi.y != 0.f) ? (OFF) + (WL) + 1 : 0;         \
                ACCF(wlo.x, o0) ACCF(wlo.y, o1) ACCF(whi.x, o2) ACCF(whi.y, o3) }
            GF(offL0, w01L0, w23L0, 128)
            GF(offL1, w01L1, w23L1, 128)
            GF(offL2, w01L2, w23L2, 128)
            GF(offL3, w01L3, w23L3, 128)
            GF(offL4, w01L4, w23L4, 64)
            GF(offL5, w01L5, w23L5, 64)
            GF(offL6, w01L6, w23L6, 64)
            GF(offL7, w01L7, w23L7, 64)
            GF(offH0, w01H0, w23H0, 32)
            GF(offH1, w01H1, w23H1, 32)
            GF(offH2, w01H2, w23H2, 32)
            GF(offH3, w01H3, w23H3, 32)
            GF(offH4, w01H4, w23H4, 16)
            GF(offH5, w01H5, w23H5, 16)
            GF(offH6, w01H6, w23H6, 16)
            GF(offH7, w01H7, w23H7, 16)
            #undef GF
            #undef ACCF
        }

        // write mid[q][chb .. chb+15] as swizzled bf16 (2 x 16B stores; r9-proven)
        const unsigned wv0 = (unsigned)f2bf(c0)  | ((unsigned)f2bf(c1)  << 16);
        const unsigned wv1 = (unsigned)f2bf(c2)  | ((unsigned)f2bf(c3)  << 16);
        const unsigned wv2 = (unsigned)f2bf(c4)  | ((unsigned)f2bf(c5)  << 16);
        const unsigned wv3 = (unsigned)f2bf(c6)  | ((unsigned)f2bf(c7)  << 16);
        const unsigned wv4 = (unsigned)f2bf(c8)  | ((unsigned)f2bf(c9)  << 16);
        const unsigned wv5 = (unsigned)f2bf(c10) | ((unsigned)f2bf(c11) << 16);
        const unsigned wv6 = (unsigned)f2bf(c12) | ((unsigned)f2bf(c13) << 16);
        const unsigned wv7 = (unsigned)f2bf(c14) | ((unsigned)f2bf(c15) << 16);
        const int sw = (q & 7) << 4;
        const u32x4 s0 = {wv0, wv1, wv2, wv3};
        const u32x4 s1 = {wv4, wv5, wv6, wv7};
        *(u32x4*)(xqb + q * 512 + ((chb * 2) ^ sw))      = s0;
        *(u32x4*)(xqb + q * 512 + ((chb * 2 + 16) ^ sw)) = s1;
    }
    __syncthreads();

    // ---- Phase E: out[q][n] = mid . Wout + bout via MFMA, direct global store ----
    {
        bf16x8 af[8];
        load_afrags(xqb, lane, af);
        const int colb = lane & 15;
        const int r0   = (lane >> 4) * 4;
        #pragma unroll
        for (int j = 0; j < 4; ++j) {
            const int tn  = wid * 4 + j;          // 0..15
            const int col = tn * 16 + colb;
            const float bv = bout[col];
            f32x4 acc = {bv, bv, bv, bv};
            const bf16x8* bp = (const bf16x8*)wsO + (size_t)tn * 8 * 64 + lane;
            #pragma unroll
            for (int s = 0; s < 8; ++s)
                acc = __builtin_amdgcn_mfma_f32_16x16x32_bf16(af[s], bp[(size_t)s * 64], acc, 0, 0, 0);
            #pragma unroll
            for (int r = 0; r < 4; ++r)
                out[(size_t)(q0 + r0 + r) * CDIM + col] = acc[r];
        }
    }
}

extern "C" void kernel_launch(void* const* d_in, const int* in_sizes, int n_in,
                              void* d_out, int out_size, void* d_ws, size_t ws_size,
                              hipStream_t stream) {
    const float* query = (const float*)d_in[0];
    const float* refp  = (const float*)d_in[1];
    const float* feat  = (const float*)d_in[2];
    const float* Woff  = (const float*)d_in[5];
    const float* boff  = (const float*)d_in[6];
    const float* Wattn = (const float*)d_in[7];
    const float* battn = (const float*)d_in[8];
    const float* Wout  = (const float*)d_in[9];
    const float* bout  = (const float*)d_in[10];
    float* out = (float*)d_out;

    unsigned short* ws = (unsigned short*)d_ws;
    const size_t feat_us = (size_t)BATCH * LQ * CDIM;        // 11,141,120 ushorts
    const size_t need    = (feat_us + 98304 + 65536) * 2;    // bytes
    const bool usebf = ws_size >= need;

    const int nrows = BATCH * LQ;            // 43520

    if (usebf) {
        unsigned short* featbf = ws;
        unsigned short* wsB = ws + feat_us;
        unsigned short* wsO = wsB + 98304;
        pack_feat<<<dim3((unsigned)(feat_us / 8 / 256)), dim3(256), 0, stream>>>(feat, featbf);
        pack_w<<<dim3(80), dim3(256), 0, stream>>>(Woff, Wattn, Wout, wsB, wsO);
        msda_fused<true><<<dim3(nrows / QT), dim3(256), 0, stream>>>(
            query, refp, feat, featbf, boff, battn, bout, wsB, wsO, out);
    } else {
        unsigned short* wsB = ws;
        unsigned short* wsO = ws + 98304;
        pack_w<<<dim3(80), dim3(256), 0, stream>>>(Woff, Wattn, Wout, wsB, wsO);
        msda_fused<false><<<dim3(nrows / QT), dim3(256), 0, stream>>>(
            query, refp, feat, (const unsigned short*)nullptr, boff, battn, bout, wsB, wsO, out);
    }
}

// Round 12
// 144.569 us; speedup vs baseline: 1.5779x; 1.0996x over previous
//
#include <hip/hip_runtime.h>
#include <hip/hip_fp16.h>
#include <math.h>

// Problem constants (fixed by setup_inputs)
#define BATCH   2
#define LQ      21760
#define CDIM    256
#define NHEADS  8
#define NLEV    4
#define NPTS    4
#define HDIM    32
#define QT      16           // queries per block; 43520/16 = 2720 blocks
#define PROJ_LDH 392         // f16 proj stride (384 cols + 8 pad)

// ===== Session journal (final) =====
// r1 scalar-f32 fused: 1203 us. r2 +MFMA GEMMs: 527. r3 +tuple precompute,
// float4 gather: 159. r4 +bf16 feat, reg tuples via shfl: 144  <-- FINAL.
// r5-r7: f16 feat + packed-half math -> deterministic absmax 0.634 across 3
//   consumer structures; f16 lane abandoned (bf16 + scalar f32 fmaf proven).
// r8: launch_bounds (256,7) -> unified VGPR+AGPR cap 73 -> spill (+500 MB
//   scratch traffic, 238 us).
// r9/r10: hoisted 16-tuple consumer at (256,4): spills at cap 128 regardless
//   of arrays vs named scalars (live-range pressure from deep load batching).
// r11: same at (256,3): spill-free (VGPR 84) but occupancy 30.9% -> 159 us.
// Model: occupancy is bound by VGPR+AGPR TOTAL (~112 here -> 4 waves/SIMD);
//   the MFMA phases' accumulators tax the gather phase. {16 waves, shallow}
//   = 144; {12 waves, deep} = 159; both-at-once hits the reg-file wall.
// Gather line utilization is 100% (64 B per corner fully consumed by the
//   d8 thread pairs) -> the ~1.43 GB L2/L3 gather traffic is irreducible
//   for this algorithm; no pipe saturates (VALU 44%, HBM 15%, L1 ~40%).

typedef short  bf16x8 __attribute__((ext_vector_type(8)));
typedef float  f32x4  __attribute__((ext_vector_type(4)));
typedef unsigned int u32x4 __attribute__((ext_vector_type(4)));
typedef unsigned short u16x8 __attribute__((ext_vector_type(8)));

static __device__ __host__ inline unsigned short f2bf(float x) {
    unsigned int u = __builtin_bit_cast(unsigned int, x);
    unsigned int r = (u + 0x7fff + ((u >> 16) & 1)) >> 16;   // RNE
    return (unsigned short)r;
}
static __device__ inline unsigned int pack2h(float a, float b) {
    __half2 h = __floats2half2_rn(a, b);
    return __builtin_bit_cast(unsigned int, h);
}
static __device__ inline float2 unpack2h(unsigned int u) {
    return __half22float2(__builtin_bit_cast(__half2, u));
}
static __device__ inline float bfhi(unsigned int u) {   // high bf16 -> f32
    return __builtin_bit_cast(float, u & 0xffff0000u);
}
static __device__ inline float bflo(unsigned int u) {   // low bf16 -> f32
    return __builtin_bit_cast(float, u << 16);
}

// ---- pack feat f32 -> bf16 into ws ----
__global__ __launch_bounds__(256) void pack_feat(
    const float* __restrict__ f, unsigned short* __restrict__ o)
{
    const size_t i8 = ((size_t)blockIdx.x * 256 + threadIdx.x) * 8;
    const float4 v0 = *(const float4*)(f + i8);
    const float4 v1 = *(const float4*)(f + i8 + 4);
    u16x8 pk;
    pk[0] = f2bf(v0.x); pk[1] = f2bf(v0.y); pk[2] = f2bf(v0.z); pk[3] = f2bf(v0.w);
    pk[4] = f2bf(v1.x); pk[5] = f2bf(v1.y); pk[6] = f2bf(v1.z); pk[7] = f2bf(v1.w);
    *(u16x8*)(o + i8) = pk;
}

// ---- pack W into bf16 B-fragment-major layout ----
__global__ __launch_bounds__(256) void pack_w(
    const float* __restrict__ Woff, const float* __restrict__ Wattn,
    const float* __restrict__ Wout, unsigned short* __restrict__ wsB,
    unsigned short* __restrict__ wsO)
{
    const int id = blockIdx.x * 256 + threadIdx.x;   // 0 .. 20479
    bf16x8 pk;
    if (id < 12288) {
        const int lane = id & 63, s = (id >> 6) & 7, tn = id >> 9;
        const int col = tn * 16 + (lane & 15);
        const int k0  = s * 32 + (lane >> 4) * 8;
        #pragma unroll
        for (int i = 0; i < 8; ++i) {
            const int k = k0 + i;
            const float w = (col < 256) ? Woff[(size_t)k * 256 + col]
                                        : Wattn[(size_t)k * 128 + (col - 256)];
            pk[i] = (short)f2bf(w);
        }
        *(bf16x8*)(wsB + (size_t)id * 8) = pk;
    } else {
        const int id2 = id - 12288;
        const int lane = id2 & 63, s = (id2 >> 6) & 7, tn = id2 >> 9;
        const int col = tn * 16 + (lane & 15);
        const int k0  = s * 32 + (lane >> 4) * 8;
        #pragma unroll
        for (int i = 0; i < 8; ++i)
            pk[i] = (short)f2bf(Wout[(size_t)(k0 + i) * 256 + col]);
        *(bf16x8*)(wsO + (size_t)id2 * 8) = pk;
    }
}

// A-frag reader: xqb is [16 rows][512 B] bf16, column-XOR-swizzled:
// element (row,k) lives at byte row*512 + ((k*2) ^ ((row&7)<<4))
static __device__ inline void load_afrags(const unsigned char* xqb, int lane, bf16x8* af) {
    const int row = lane & 15;
    const int kg8 = (lane >> 4) * 8;
    const int sw  = (row & 7) << 4;
    const int base = row * 512;
    #pragma unroll
    for (int s = 0; s < 8; ++s) {
        const int byte = base + (((s * 32 + kg8) * 2) ^ sw);
        af[s] = *(const bf16x8*)(xqb + byte);
    }
}

template<bool BF16F>
__global__ __launch_bounds__(256, 5) void msda_fused(
    const float* __restrict__ query,     // [B][LQ][256]
    const float* __restrict__ refp,      // [B][LQ][2]
    const float* __restrict__ feat,      // [B][LQ][256] f32
    const unsigned short* __restrict__ featbf,   // [B][LQ][256] bf16 (if BF16F)
    const float* __restrict__ boff,      // [256]
    const float* __restrict__ battn,     // [128]
    const float* __restrict__ bout,      // [256]
    const unsigned short* __restrict__ wsB,   // packed [Woff|Wattn] frags
    const unsigned short* __restrict__ wsO,   // packed Wout frags
    float* __restrict__ out)             // [B][LQ][256]
{
    __shared__ __align__(16) unsigned char xqb[QT * 512];   // bf16 A-tile (query, then mid)
    __shared__ __align__(16) __half projh[QT * PROJ_LDH];   // f16 [off(256)|attn(128)] per q

    const int t    = threadIdx.x;
    const int lane = t & 63;
    const int wid  = t >> 6;
    const int q0   = blockIdx.x * QT;
    const int b    = q0 / LQ;

    // ---- Phase A: stage 16 query rows as swizzled bf16 ----
    {
        const float4* src = (const float4*)(query + (size_t)q0 * CDIM);
        #pragma unroll
        for (int i = 0; i < 4; ++i) {
            const int idx = t + i * 256;          // 0..1023 float4s
            const int row = idx >> 6;             // 64 float4 per row
            const int k4  = (idx & 63) * 4;       // element k base
            const float4 v = src[idx];
            uint2 w;
            w.x = (unsigned int)f2bf(v.x) | ((unsigned int)f2bf(v.y) << 16);
            w.y = (unsigned int)f2bf(v.z) | ((unsigned int)f2bf(v.w) << 16);
            const int byte = row * 512 + ((k4 * 2) ^ ((row & 7) << 4));
            *(uint2*)(xqb + byte) = w;
        }
    }
    __syncthreads();

    // ---- Phase B: projh[q][c] = query . [Woff|Wattn] + bias via MFMA ----
    {
        bf16x8 af[8];
        load_afrags(xqb, lane, af);
        const int colb = lane & 15;
        const int r0   = (lane >> 4) * 4;
        #pragma unroll
        for (int j = 0; j < 6; ++j) {
            const int tn  = wid * 6 + j;          // 0..23
            const int col = tn * 16 + colb;
            const float bv = (col < 256) ? boff[col] : battn[col - 256];
            f32x4 acc = {bv, bv, bv, bv};
            const bf16x8* bp = (const bf16x8*)wsB + (size_t)tn * 8 * 64 + lane;
            #pragma unroll
            for (int s = 0; s < 8; ++s)
                acc = __builtin_amdgcn_mfma_f32_16x16x32_bf16(af[s], bp[(size_t)s * 64], acc, 0, 0, 0);
            #pragma unroll
            for (int r = 0; r < 4; ++r)
                projh[(r0 + r) * PROJ_LDH + col] = __float2half(acc[r]);
        }
    }
    __syncthreads();

    // ---- Phase C: softmax over the 16 attn logits per (q, h) ----
    if (t < QT * NHEADS) {
        const int q = t >> 3, h = t & 7;
        __half* a = projh + q * PROJ_LDH + 256 + h * 16;
        float v[16];
        #pragma unroll
        for (int j = 0; j < 16; ++j) v[j] = __half2float(a[j]);
        float m = v[0];
        #pragma unroll
        for (int j = 1; j < 16; ++j) m = fmaxf(m, v[j]);
        float s = 0.f;
        #pragma unroll
        for (int j = 0; j < 16; ++j) { v[j] = __expf(v[j] - m); s += v[j]; }
        const float inv = 1.f / s;
        #pragma unroll
        for (int j = 0; j < 16; ++j) a[j] = __float2half(v[j] * inv);
    }
    __syncthreads();

    // ---- Phase D0: each thread builds 8 tuples for its (q_own, h_own, half) ----
    // tuple (q,h,lp) lives in lane (q&3)*16 + h*2 + (lp>>3), register k = lp&7
    int r_off[8]; int r_w01[8]; int r_w23[8];
    {
        const int q_own = t >> 4;
        const int h_own = (t >> 1) & 7;
        const int lpb   = (t & 1) * 8;
        const float rx = refp[(size_t)(q0 + q_own) * 2 + 0];
        const float ry = refp[(size_t)(q0 + q_own) * 2 + 1];
        const int LW[4] = {128, 64, 32, 16};
        const int LS[4] = {0, 16384, 20480, 21504};
        #pragma unroll
        for (int k = 0; k < 8; ++k) {
            const int lp = lpb + k;
            const int l = lp >> 2, p = lp & 3;
            const int Wl = LW[l], Hl = LW[l];
            const unsigned int oxy = *(const unsigned int*)(projh + q_own * PROJ_LDH
                                        + ((h_own * NLEV + l) * NPTS + p) * 2);
            const float2 oo = unpack2h(oxy);
            const float aw = __half2float(projh[q_own * PROJ_LDH + 256 + h_own * 16 + lp]);
            const float x = rx * (float)Wl + oo.x - 0.5f;
            const float y = ry * (float)Hl + oo.y - 0.5f;
            const float x0f = floorf(x), y0f = floorf(y);
            const float fx = x - x0f, fy = y - y0f;
            const int ix = (int)x0f, iy = (int)y0f;
            const bool vx0 = (ix >= 0) & (ix < Wl), vx1 = (ix >= -1) & (ix < Wl - 1);
            const bool vy0 = (iy >= 0) & (iy < Hl), vy1 = (iy >= -1) & (iy < Hl - 1);
            const float w00 = (vx0 & vy0) ? (1.f - fx) * (1.f - fy) * aw : 0.f;
            const float w01 = (vx1 & vy0) ? fx * (1.f - fy) * aw : 0.f;
            const float w10 = (vx0 & vy1) ? (1.f - fx) * fy * aw : 0.f;
            const float w11 = (vx1 & vy1) ? fx * fy * aw : 0.f;
            r_off[k] = LS[l] + iy * Wl + ix;
            r_w01[k] = (int)pack2h(w00, w01);
            r_w23[k] = (int)pack2h(w10, w11);
        }
    }
    // no barrier needed: producers and consumers are in the same wave

    // ---- Phase D1: gather; thread -> (d8 = t&3, h = (t>>2)&7, qpar = (t>>5)&1) ----
    {
        const int d8   = t & 3;
        const int h    = (t >> 2) & 7;
        const int qpar = (t >> 5) & 1;
        const int qg   = t >> 6;
        const int chb  = h * HDIM + d8 * 8;       // channel base
        #pragma unroll
        for (int j = 0; j < 2; ++j) {
            const int q = qg * 4 + j * 2 + qpar;
            const int srcb = (q & 3) * 16 + h * 2;
            float a0 = 0.f, a1 = 0.f, a2 = 0.f, a3 = 0.f;
            float a4 = 0.f, a5 = 0.f, a6 = 0.f, a7 = 0.f;
            #pragma unroll
            for (int lp = 0; lp < 16; ++lp) {
                const int k = lp & 7;
                const int src = srcb + (lp >> 3);
                const int Wl = (lp < 4) ? 128 : (lp < 8) ? 64 : (lp < 12) ? 32 : 16;
                const int off00 = __shfl(r_off[k], src);
                const float2 wlo = unpack2h((unsigned int)__shfl(r_w01[k], src));
                const float2 whi = unpack2h((unsigned int)__shfl(r_w23[k], src));
                const int o0 = (wlo.x != 0.f) ? off00          : 0;
                const int o1 = (wlo.y != 0.f) ? off00 + 1      : 0;
                const int o2 = (whi.x != 0.f) ? off00 + Wl     : 0;
                const int o3 = (whi.y != 0.f) ? off00 + Wl + 1 : 0;
                if (BF16F) {
                    const unsigned short* fb = featbf + (size_t)b * LQ * CDIM + chb;
                    const u32x4 v0 = *(const u32x4*)(fb + (long)o0 * CDIM);
                    const u32x4 v1 = *(const u32x4*)(fb + (long)o1 * CDIM);
                    const u32x4 v2 = *(const u32x4*)(fb + (long)o2 * CDIM);
                    const u32x4 v3 = *(const u32x4*)(fb + (long)o3 * CDIM);
                    a0 = fmaf(wlo.x, bflo(v0[0]), a0); a1 = fmaf(wlo.x, bfhi(v0[0]), a1);
                    a2 = fmaf(wlo.x, bflo(v0[1]), a2); a3 = fmaf(wlo.x, bfhi(v0[1]), a3);
                    a4 = fmaf(wlo.x, bflo(v0[2]), a4); a5 = fmaf(wlo.x, bfhi(v0[2]), a5);
                    a6 = fmaf(wlo.x, bflo(v0[3]), a6); a7 = fmaf(wlo.x, bfhi(v0[3]), a7);
                    a0 = fmaf(wlo.y, bflo(v1[0]), a0); a1 = fmaf(wlo.y, bfhi(v1[0]), a1);
                    a2 = fmaf(wlo.y, bflo(v1[1]), a2); a3 = fmaf(wlo.y, bfhi(v1[1]), a3);
                    a4 = fmaf(wlo.y, bflo(v1[2]), a4); a5 = fmaf(wlo.y, bfhi(v1[2]), a5);
                    a6 = fmaf(wlo.y, bflo(v1[3]), a6); a7 = fmaf(wlo.y, bfhi(v1[3]), a7);
                    a0 = fmaf(whi.x, bflo(v2[0]), a0); a1 = fmaf(whi.x, bfhi(v2[0]), a1);
                    a2 = fmaf(whi.x, bflo(v2[1]), a2); a3 = fmaf(whi.x, bfhi(v2[1]), a3);
                    a4 = fmaf(whi.x, bflo(v2[2]), a4); a5 = fmaf(whi.x, bfhi(v2[2]), a5);
                    a6 = fmaf(whi.x, bflo(v2[3]), a6); a7 = fmaf(whi.x, bfhi(v2[3]), a7);
                    a0 = fmaf(whi.y, bflo(v3[0]), a0); a1 = fmaf(whi.y, bfhi(v3[0]), a1);
                    a2 = fmaf(whi.y, bflo(v3[1]), a2); a3 = fmaf(whi.y, bfhi(v3[1]), a3);
                    a4 = fmaf(whi.y, bflo(v3[2]), a4); a5 = fmaf(whi.y, bfhi(v3[2]), a5);
                    a6 = fmaf(whi.y, bflo(v3[3]), a6); a7 = fmaf(whi.y, bfhi(v3[3]), a7);
                } else {
                    const float* fb = feat + (size_t)b * LQ * CDIM + chb;
                    const f32x4 v0a = *(const f32x4*)(fb + (long)o0 * CDIM);
                    const f32x4 v0b = *(const f32x4*)(fb + (long)o0 * CDIM + 4);
                    const f32x4 v1a = *(const f32x4*)(fb + (long)o1 * CDIM);
                    const f32x4 v1b = *(const f32x4*)(fb + (long)o1 * CDIM + 4);
                    const f32x4 v2a = *(const f32x4*)(fb + (long)o2 * CDIM);
                    const f32x4 v2b = *(const f32x4*)(fb + (long)o2 * CDIM + 4);
                    const f32x4 v3a = *(const f32x4*)(fb + (long)o3 * CDIM);
                    const f32x4 v3b = *(const f32x4*)(fb + (long)o3 * CDIM + 4);
                    a0 = fmaf(wlo.x, v0a[0], a0); a1 = fmaf(wlo.x, v0a[1], a1);
                    a2 = fmaf(wlo.x, v0a[2], a2); a3 = fmaf(wlo.x, v0a[3], a3);
                    a4 = fmaf(wlo.x, v0b[0], a4); a5 = fmaf(wlo.x, v0b[1], a5);
                    a6 = fmaf(wlo.x, v0b[2], a6); a7 = fmaf(wlo.x, v0b[3], a7);
                    a0 = fmaf(wlo.y, v1a[0], a0); a1 = fmaf(wlo.y, v1a[1], a1);
                    a2 = fmaf(wlo.y, v1a[2], a2); a3 = fmaf(wlo.y, v1a[3], a3);
                    a4 = fmaf(wlo.y, v1b[0], a4); a5 = fmaf(wlo.y, v1b[1], a5);
                    a6 = fmaf(wlo.y, v1b[2], a6); a7 = fmaf(wlo.y, v1b[3], a7);
                    a0 = fmaf(whi.x, v2a[0], a0); a1 = fmaf(whi.x, v2a[1], a1);
                    a2 = fmaf(whi.x, v2a[2], a2); a3 = fmaf(whi.x, v2a[3], a3);
                    a4 = fmaf(whi.x, v2b[0], a4); a5 = fmaf(whi.x, v2b[1], a5);
                    a6 = fmaf(whi.x, v2b[2], a6); a7 = fmaf(whi.x, v2b[3], a7);
                    a0 = fmaf(whi.y, v3a[0], a0); a1 = fmaf(whi.y, v3a[1], a1);
                    a2 = fmaf(whi.y, v3a[2], a2); a3 = fmaf(whi.y, v3a[3], a3);
                    a4 = fmaf(whi.y, v3b[0], a4); a5 = fmaf(whi.y, v3b[1], a5);
                    a6 = fmaf(whi.y, v3b[2], a6); a7 = fmaf(whi.y, v3b[3], a7);
                }
            }
            // write mid[q][chb .. chb+7] as swizzled bf16 (16B store)
            u32x4 wv;
            wv[0] = (unsigned int)f2bf(a0) | ((unsigned int)f2bf(a1) << 16);
            wv[1] = (unsigned int)f2bf(a2) | ((unsigned int)f2bf(a3) << 16);
            wv[2] = (unsigned int)f2bf(a4) | ((unsigned int)f2bf(a5) << 16);
            wv[3] = (unsigned int)f2bf(a6) | ((unsigned int)f2bf(a7) << 16);
            const int byte = q * 512 + (((chb) * 2) ^ ((q & 7) << 4));
            *(u32x4*)(xqb + byte) = wv;
        }
    }
    __syncthreads();

    // ---- Phase E: out[q][n] = mid . Wout + bout via MFMA, direct global store ----
    {
        bf16x8 af[8];
        load_afrags(xqb, lane, af);
        const int colb = lane & 15;
        const int r0   = (lane >> 4) * 4;
        #pragma unroll
        for (int j = 0; j < 4; ++j) {
            const int tn  = wid * 4 + j;          // 0..15
            const int col = tn * 16 + colb;
            const float bv = bout[col];
            f32x4 acc = {bv, bv, bv, bv};
            const bf16x8* bp = (const bf16x8*)wsO + (size_t)tn * 8 * 64 + lane;
            #pragma unroll
            for (int s = 0; s < 8; ++s)
                acc = __builtin_amdgcn_mfma_f32_16x16x32_bf16(af[s], bp[(size_t)s * 64], acc, 0, 0, 0);
            #pragma unroll
            for (int r = 0; r < 4; ++r)
                out[(size_t)(q0 + r0 + r) * CDIM + col] = acc[r];
        }
    }
}

extern "C" void kernel_launch(void* const* d_in, const int* in_sizes, int n_in,
                              void* d_out, int out_size, void* d_ws, size_t ws_size,
                              hipStream_t stream) {
    const float* query = (const float*)d_in[0];
    const float* refp  = (const float*)d_in[1];
    const float* feat  = (const float*)d_in[2];
    const float* Woff  = (const float*)d_in[5];
    const float* boff  = (const float*)d_in[6];
    const float* Wattn = (const float*)d_in[7];
    const float* battn = (const float*)d_in[8];
    const float* Wout  = (const float*)d_in[9];
    const float* bout  = (const float*)d_in[10];
    float* out = (float*)d_out;

    unsigned short* ws = (unsigned short*)d_ws;
    const size_t feat_us = (size_t)BATCH * LQ * CDIM;        // 11,141,120 ushorts
    const size_t need    = (feat_us + 98304 + 65536) * 2;    // bytes
    const bool usebf = ws_size >= need;

    const int nrows = BATCH * LQ;            // 43520

    if (usebf) {
        unsigned short* featbf = ws;
        unsigned short* wsB = ws + feat_us;
        unsigned short* wsO = wsB + 98304;
        pack_feat<<<dim3((unsigned)(feat_us / 8 / 256)), dim3(256), 0, stream>>>(feat, featbf);
        pack_w<<<dim3(80), dim3(256), 0, stream>>>(Woff, Wattn, Wout, wsB, wsO);
        msda_fused<true><<<dim3(nrows / QT), dim3(256), 0, stream>>>(
            query, refp, feat, featbf, boff, battn, bout, wsB, wsO, out);
    } else {
        unsigned short* wsB = ws;
        unsigned short* wsO = ws + 98304;
        pack_w<<<dim3(80), dim3(256), 0, stream>>>(Woff, Wattn, Wout, wsB, wsO);
        msda_fused<false><<<dim3(nrows / QT), dim3(256), 0, stream>>>(
            query, refp, feat, (const unsigned short*)nullptr, boff, battn, bout, wsB, wsO, out);
    }
}